// Round 5
// baseline (313.939 us; speedup 1.0000x reference)
//
#include <hip/hip_runtime.h>
#include <hip/hip_bf16.h>
#include <math.h>

#define NN 50000
#define NE 800000
#define ETOT (NE + NN)      // 850000, self-loops appended after edges
#define NPAD 50176          // 196*256, padded node count for int4 scan
#define CLS 40
#define CLSP 48             // layer-2 channels padded to 48
#define NEG 0.2f
#define MTILES (NN / 16)    // 3125 exact
#define GB1 ((MTILES + 3) / 4)   // 782 gemm blocks
#define PREPB 196           // prep blocks: max(45056 weights, 50176 deg-init)/256
#define CNTB 196            // count blocks: ceil(NE/4096)
#define SCB 208             // scatter blocks: ceil(ETOT/4096)
#define NHALF (NN / 2)      // 25000: node kernels split into two dispatches

#define L2E 1.44269504088896f
#define C06 (0.6f * L2E)
#define C04 (0.4f * L2E)

typedef __hip_bfloat16 bf16;
typedef __attribute__((ext_vector_type(8))) __bf16 bf16x8;
typedef __attribute__((ext_vector_type(4))) float f32x4;
typedef __attribute__((ext_vector_type(2))) float f32x2;
struct U3 { unsigned x, y, z; };   // 12B, 4-aligned

__device__ __forceinline__ bf16x8 cvt8(f32x4 a, f32x4 b) {
    bf16x8 r;
    r[0] = (__bf16)a[0]; r[1] = (__bf16)a[1]; r[2] = (__bf16)a[2]; r[3] = (__bf16)a[3];
    r[4] = (__bf16)b[0]; r[5] = (__bf16)b[1]; r[6] = (__bf16)b[2]; r[7] = (__bf16)b[3];
    return r;
}
// 2 packed bf16 (one u32) -> f32x2 (register pair feeding v_pk_* ops)
__device__ __forceinline__ f32x2 unpk2(unsigned u) {
    f32x2 r;
    r.x = __uint_as_float(u << 16);
    r.y = __uint_as_float(u & 0xffff0000u);
    return r;
}

// 256-entry exclusive scan (4 waves). Returns exclusive prefix of v.
__device__ __forceinline__ unsigned scan256(unsigned v, unsigned* wsum) {
    int t = threadIdx.x;
    int lane = t & 63, w = t >> 6;
    unsigned inc = v;
#pragma unroll
    for (int d = 1; d < 64; d <<= 1) {
        unsigned x = __shfl_up(inc, d);
        if (lane >= d) inc += x;
    }
    if (lane == 63) wsum[w] = inc;
    __syncthreads();
    unsigned woff = 0;
#pragma unroll
    for (int i = 0; i < 4; i++) woff += (i < w) ? wsum[i] : 0;
    return woff + inc - v;
}

// ---- K1: weight prep (fp32->bf16 transposed) + deg init (self-loop = 1). ----
__global__ __launch_bounds__(256) void prep(
        const float* __restrict__ w1l, const float* __restrict__ w1r,
        const float* __restrict__ w2l, const float* __restrict__ w2r,
        bf16* __restrict__ wT1, bf16* __restrict__ wT2,
        int* __restrict__ degA) {
    int t = blockIdx.x * 256 + threadIdx.x;
    if (t < NPAD) degA[t] = (t < NN) ? 1 : 0;   // self-loop counted up front
    if (t < 2 * 128 * 128) {
        int m = t >> 14;
        int idx = t & 16383;
        int n = idx >> 7, k = idx & 127;
        const float* w = m ? w1r : w1l;
        wT1[t] = __float2bfloat16(w[k * 128 + n]);
    } else if (t < 2 * 128 * 128 + 2 * CLSP * 128) {
        int u = t - 2 * 128 * 128;
        int m = u / (CLSP * 128);
        int idx = u % (CLSP * 128);
        int n = idx >> 7, k = idx & 127;
        const float* w = m ? w2r : w2l;
        wT2[u] = __float2bfloat16((n < CLS) ? w[k * CLS + n] : 0.0f);
    }
}

// ---- K2: GEMM1 dual (xl1,xr1 = x @ w1{l,r})  ||  degree count. ----
// No LDS in either branch -> no occupancy cap, genuine overlap between the
// MFMA-heavy gemm blocks and the atomic-heavy count blocks.
__global__ __launch_bounds__(256) void gemm1_count(
        const float* __restrict__ x, const bf16* __restrict__ wT,
        bf16* __restrict__ outL, bf16* __restrict__ outR,
        const int* __restrict__ ei, int* __restrict__ degA) {
    if ((int)blockIdx.x < GB1) {
        int wave = threadIdx.x >> 6;
        int lane = threadIdx.x & 63;
        int tile = blockIdx.x * 4 + wave;
        if (tile >= MTILES) return;
        const bf16* wl = wT;
        const bf16* wr = wT + 128 * 128;
        int row0 = tile * 16;
        int l16 = lane & 15, quad = lane >> 4;
        f32x4 z = {0.f, 0.f, 0.f, 0.f};
        f32x4 accl[8], accr[8];
#pragma unroll
        for (int i = 0; i < 8; i++) { accl[i] = z; accr[i] = z; }
        const float* xrow = x + (size_t)(row0 + l16) * 128 + quad * 8;
#pragma unroll
        for (int k0 = 0; k0 < 128; k0 += 32) {
            f32x4 a0 = *reinterpret_cast<const f32x4*>(xrow + k0);
            f32x4 a1v = *reinterpret_cast<const f32x4*>(xrow + k0 + 4);
            bf16x8 a = cvt8(a0, a1v);
#pragma unroll
            for (int ct = 0; ct < 8; ct++) {
                bf16x8 bl = *reinterpret_cast<const bf16x8*>(wl + (ct * 16 + l16) * 128 + k0 + quad * 8);
                bf16x8 br = *reinterpret_cast<const bf16x8*>(wr + (ct * 16 + l16) * 128 + k0 + quad * 8);
                accl[ct] = __builtin_amdgcn_mfma_f32_16x16x32_bf16(a, bl, accl[ct], 0, 0, 0);
                accr[ct] = __builtin_amdgcn_mfma_f32_16x16x32_bf16(a, br, accr[ct], 0, 0, 0);
            }
        }
#pragma unroll
        for (int ct = 0; ct < 8; ct++)
#pragma unroll
            for (int r = 0; r < 4; r++) {
                size_t o = (size_t)(row0 + quad * 4 + r) * 128 + ct * 16 + l16;
                outL[o] = __float2bfloat16(accl[ct][r]);
                outR[o] = __float2bfloat16(accr[ct][r]);
            }
    } else {
        int t = threadIdx.x;
        int e0 = ((int)blockIdx.x - GB1) * 4096;
#pragma unroll
        for (int i = 0; i < 16; i++) {
            int e = e0 + i * 256 + t;
            if (e < NE) atomicAdd(&degA[ei[NE + e]], 1);
        }
    }
}

// ---- K3: exclusive scan over degrees -> startA, cursor. One block. ----
__global__ __launch_bounds__(256) void scan_deg(const int* __restrict__ degA,
                                                int* __restrict__ startA,
                                                int* __restrict__ cursor) {
    __shared__ unsigned wsum[4];
    int t = threadIdx.x;
    const int4* d4 = reinterpret_cast<const int4*>(degA) + t * 49;   // 49*4 = 196 nodes/thread
    int s = 0;
#pragma unroll 7
    for (int i = 0; i < 49; i++) {
        int4 v = d4[i];
        s += v.x + v.y + v.z + v.w;
    }
    int run = (int)scan256((unsigned)s, wsum);
    int4* s4 = reinterpret_cast<int4*>(startA) + t * 49;
    int4* c4 = reinterpret_cast<int4*>(cursor) + t * 49;
#pragma unroll 7
    for (int i = 0; i < 49; i++) {
        int4 v = d4[i];
        int4 o;
        o.x = run; run += v.x;
        o.y = run; run += v.y;
        o.z = run; run += v.z;
        o.w = run; run += v.w;
        s4[i] = o;
        c4[i] = o;
    }
}

// ---- K4: edge scatter into dense CSR (counting sort, order-insensitive). ----
__global__ __launch_bounds__(256) void scatter(const int* __restrict__ ei,
                                               int* __restrict__ cursor,
                                               int* __restrict__ csr_src) {
    int t = threadIdx.x;
    int e0 = blockIdx.x * 4096;
#pragma unroll
    for (int i = 0; i < 16; i++) {
        int e = e0 + i * 256 + t;
        if (e < ETOT) {
            int s, d;
            if (e < NE) { s = ei[e]; d = ei[NE + e]; }
            else        { s = d = e - NE; }
            int pos = atomicAdd(&cursor[d], 1);
            csr_src[pos] = s;
        }
    }
}

// ---- K5: layer 1 fused. One wave/node, 16 lanes/edge, up to 32 edges in flight. ----
// Packed-fp32 math: leaky(v)=0.6v+0.4|v|; logit uses v_pk_fma for the 0.6-dot
// and scalar v_fma with free |t| modifier for the 0.4-dot; log2e prefolded
// into the coefficients so exp is a single v_exp_f32. The accumulator sums
// w*t (t = xl[src]+xr[dst]); epilogue corrects acc/s - xr = sum(w*xl)/s.
struct L1S { float s; f32x2 acc[4]; };
__device__ __forceinline__ void l1_consume(uint4 u, bool valid, const f32x2* xrp,
                                           const f32x2* a06, const float* a04, L1S& st) {
    f32x2 t0 = unpk2(u.x) + xrp[0];
    f32x2 t1 = unpk2(u.y) + xrp[1];
    f32x2 t2 = unpk2(u.z) + xrp[2];
    f32x2 t3 = unpk2(u.w) + xrp[3];
    f32x2 ep = t0 * a06[0];
    ep = __builtin_elementwise_fma(t1, a06[1], ep);
    ep = __builtin_elementwise_fma(t2, a06[2], ep);
    ep = __builtin_elementwise_fma(t3, a06[3], ep);
    float e0 = fmaf(a04[1], fabsf(t0.y), a04[0] * fabsf(t0.x));
    e0 = fmaf(a04[2], fabsf(t1.x), e0);
    e0 = fmaf(a04[3], fabsf(t1.y), e0);
    float e1 = fmaf(a04[5], fabsf(t2.y), a04[4] * fabsf(t2.x));
    e1 = fmaf(a04[6], fabsf(t3.x), e1);
    e1 = fmaf(a04[7], fabsf(t3.y), e1);
    float e = (ep.x + ep.y) + (e0 + e1);
    e += __shfl_xor(e, 1);
    e += __shfl_xor(e, 2);          // per-head logit (4-lane quad)
    float w = valid ? __builtin_amdgcn_exp2f(e) : 0.f;
    st.s += w;
    f32x2 wv = {w, w};
    st.acc[0] = __builtin_elementwise_fma(wv, t0, st.acc[0]);
    st.acc[1] = __builtin_elementwise_fma(wv, t1, st.acc[1]);
    st.acc[2] = __builtin_elementwise_fma(wv, t2, st.acc[2]);
    st.acc[3] = __builtin_elementwise_fma(wv, t3, st.acc[3]);
}

__global__ __launch_bounds__(256) void node_l1(const int* __restrict__ startA,
                                               const int* __restrict__ degA,
                                               const int* __restrict__ csr_src,
                                               const bf16* __restrict__ xl,
                                               const bf16* __restrict__ xr,
                                               const float* __restrict__ a1,
                                               const float* __restrict__ b1,
                                               bf16* __restrict__ hb,
                                               int nbase) {
    int wid = nbase + ((blockIdx.x * 256 + threadIdx.x) >> 6);
    int lane = threadIdx.x & 63;
    int g = lane >> 4, t = lane & 15;
    unsigned cB = (unsigned)t * 16;
    int j0 = startA[wid];
    int deg = degA[wid];
    unsigned rowB = (unsigned)csr_src[j0 + min(lane, deg - 1)] << 8;
    const char* xlb = (const char*)xl;
    f32x2 xrp[4];
    {
        uint4 raw = *(const uint4*)((const char*)xr + ((unsigned)wid << 8) + cB);
        xrp[0] = unpk2(raw.x); xrp[1] = unpk2(raw.y);
        xrp[2] = unpk2(raw.z); xrp[3] = unpk2(raw.w);
    }
    f32x2 a06[4];
    float a04[8];
    {
        f32x4 lo = *reinterpret_cast<const f32x4*>(a1 + t * 8);
        f32x4 hi = *reinterpret_cast<const f32x4*>(a1 + t * 8 + 4);
        float af[8];
#pragma unroll
        for (int k = 0; k < 4; k++) { af[k] = lo[k]; af[k + 4] = hi[k]; }
#pragma unroll
        for (int j = 0; j < 4; j++) {
            a06[j].x = af[2 * j] * C06;
            a06[j].y = af[2 * j + 1] * C06;
        }
#pragma unroll
        for (int k = 0; k < 8; k++) a04[k] = af[k] * C04;
    }
    L1S st; st.s = 0.f;
    f32x2 z2 = {0.f, 0.f};
#pragma unroll
    for (int k = 0; k < 4; k++) st.acc[k] = z2;
    int nb = (deg + 3) >> 2;      // 4 edges per batch, one per 16-lane group
    uint4 u[8];
    // Round 1: batches 0-3 (edges 0-15), addresses clamped so loads are
    // always valid; overshoot slots re-read the last row (L1-hot).
#pragma unroll
    for (int i = 0; i < 4; i++) {
        int pp = min(i * 4 + g, deg - 1);     // <= 31, shfl-safe
        u[i] = *(const uint4*)(xlb + (__shfl(rowB, pp) + cB));
    }
    if (nb > 4) {
        // Round 2 loads issue BEFORE any consume: up to 32 edges in flight.
#pragma unroll
        for (int i = 4; i < 8; i++) {
            int pp = min(i * 4 + g, deg - 1); // <= 31, shfl-safe
            u[i] = *(const uint4*)(xlb + (__shfl(rowB, pp) + cB));
        }
    }
    l1_consume(u[0], g < deg, xrp, a06, a04, st);
    if (nb > 1) l1_consume(u[1], 4 + g < deg, xrp, a06, a04, st);
    if (nb > 2) l1_consume(u[2], 8 + g < deg, xrp, a06, a04, st);
    if (nb > 3) l1_consume(u[3], 12 + g < deg, xrp, a06, a04, st);
    if (nb > 4) {
        l1_consume(u[4], 16 + g < deg, xrp, a06, a04, st);
        if (nb > 5) l1_consume(u[5], 20 + g < deg, xrp, a06, a04, st);
        if (nb > 6) l1_consume(u[6], 24 + g < deg, xrp, a06, a04, st);
        if (nb > 7) l1_consume(u[7], 28 + g < deg, xrp, a06, a04, st);
        // deg > 32: rare serial fallback (handles deg > 64 too).
        for (int b = 8; b < nb; b++) {
            int p = b * 4 + g;
            bool valid = p < deg;
            int pp = valid ? p : deg - 1;
            unsigned o = __shfl(rowB, min(pp, 63)) + cB;
            if (pp >= 64) o = (((unsigned)csr_src[j0 + pp]) << 8) + cB;
            uint4 uu = *(const uint4*)(xlb + o);
            l1_consume(uu, valid, xrp, a06, a04, st);
        }
    }
#pragma unroll
    for (int d = 16; d < 64; d <<= 1) {
        st.s += __shfl_xor(st.s, d);
#pragma unroll
        for (int k = 0; k < 4; k++) {
            st.acc[k].x += __shfl_xor(st.acc[k].x, d);
            st.acc[k].y += __shfl_xor(st.acc[k].y, d);
        }
    }
    if (g == 0) {
        float inv = 1.f / st.s;
        unsigned pk[4];
#pragma unroll
        for (int k = 0; k < 4; k++) {
            float o0 = st.acc[k].x * inv - xrp[k].x + b1[t * 8 + 2 * k];
            float o1 = st.acc[k].y * inv - xrp[k].y + b1[t * 8 + 2 * k + 1];
            o0 = o0 > 0.f ? o0 : __expf(o0) - 1.f;
            o1 = o1 > 0.f ? o1 : __expf(o1) - 1.f;
            bf16 r0 = __float2bfloat16(o0), r1 = __float2bfloat16(o1);
            pk[k] = (unsigned)*reinterpret_cast<unsigned short*>(&r0) |
                    ((unsigned)*reinterpret_cast<unsigned short*>(&r1) << 16);
        }
        uint4 w4 = {pk[0], pk[1], pk[2], pk[3]};
        *(uint4*)((char*)hb + ((unsigned)wid << 8) + cB) = w4;
    }
}

// ---- K6: GEMM2 dual: xl2p/xr2p = h @ w2{l,r}(128x48 zero-padded), stride 48. ----
__global__ __launch_bounds__(256) void gemm2(const bf16* __restrict__ h,
                                             const bf16* __restrict__ wT,
                                             bf16* __restrict__ outL,
                                             bf16* __restrict__ outR) {
    int wave = threadIdx.x >> 6;
    int lane = threadIdx.x & 63;
    int tile = blockIdx.x * 4 + wave;
    if (tile >= MTILES) return;
    const bf16* wl = wT;
    const bf16* wr = wT + CLSP * 128;
    int row0 = tile * 16;
    int l16 = lane & 15, quad = lane >> 4;
    f32x4 z = {0.f, 0.f, 0.f, 0.f};
    f32x4 accl[3], accr[3];
#pragma unroll
    for (int i = 0; i < 3; i++) { accl[i] = z; accr[i] = z; }
    const bf16* hrow = h + (size_t)(row0 + l16) * 128 + quad * 8;
#pragma unroll
    for (int k0 = 0; k0 < 128; k0 += 32) {
        bf16x8 a = *reinterpret_cast<const bf16x8*>(hrow + k0);
#pragma unroll
        for (int ct = 0; ct < 3; ct++) {
            bf16x8 bl = *reinterpret_cast<const bf16x8*>(wl + (ct * 16 + l16) * 128 + k0 + quad * 8);
            bf16x8 br = *reinterpret_cast<const bf16x8*>(wr + (ct * 16 + l16) * 128 + k0 + quad * 8);
            accl[ct] = __builtin_amdgcn_mfma_f32_16x16x32_bf16(a, bl, accl[ct], 0, 0, 0);
            accr[ct] = __builtin_amdgcn_mfma_f32_16x16x32_bf16(a, br, accr[ct], 0, 0, 0);
        }
    }
#pragma unroll
    for (int ct = 0; ct < 3; ct++)
#pragma unroll
        for (int r = 0; r < 4; r++) {
            size_t o = (size_t)(row0 + quad * 4 + r) * CLSP + ct * 16 + l16;
            outL[o] = __float2bfloat16(accl[ct][r]);
            outR[o] = __float2bfloat16(accr[ct][r]);
        }
}

// ---- K7: layer 2 fused. One wave/node, 8 lanes/edge, up to 32 edges in flight. ----
struct L2S { float s; f32x2 acc[3]; };
__device__ __forceinline__ void l2_consume(U3 u, bool valid, const f32x2* xrp,
                                           const f32x2* a06, const float* a04, L2S& st) {
    f32x2 t0 = unpk2(u.x) + xrp[0];
    f32x2 t1 = unpk2(u.y) + xrp[1];
    f32x2 t2 = unpk2(u.z) + xrp[2];
    f32x2 ep = t0 * a06[0];
    ep = __builtin_elementwise_fma(t1, a06[1], ep);
    ep = __builtin_elementwise_fma(t2, a06[2], ep);
    float es = fmaf(a04[1], fabsf(t0.y), a04[0] * fabsf(t0.x));
    es = fmaf(a04[2], fabsf(t1.x), es);
    es = fmaf(a04[3], fabsf(t1.y), es);
    es = fmaf(a04[4], fabsf(t2.x), es);
    es = fmaf(a04[5], fabsf(t2.y), es);
    float e = (ep.x + ep.y) + es;
    e += __shfl_xor(e, 1);
    e += __shfl_xor(e, 2);
    e += __shfl_xor(e, 4);          // full 48-ch logit (8-lane group)
    float w = valid ? __builtin_amdgcn_exp2f(e) : 0.f;
    st.s += w;
    f32x2 wv = {w, w};
    st.acc[0] = __builtin_elementwise_fma(wv, t0, st.acc[0]);
    st.acc[1] = __builtin_elementwise_fma(wv, t1, st.acc[1]);
    st.acc[2] = __builtin_elementwise_fma(wv, t2, st.acc[2]);
}

__global__ __launch_bounds__(256) void node_l2(const int* __restrict__ startA,
                                               const int* __restrict__ degA,
                                               const int* __restrict__ csr_src,
                                               const bf16* __restrict__ xl2,
                                               const bf16* __restrict__ xr2,
                                               const float* __restrict__ a2,
                                               const float* __restrict__ b2,
                                               float* __restrict__ out,
                                               int nbase) {
    int wid = nbase + ((blockIdx.x * 256 + threadIdx.x) >> 6);
    int lane = threadIdx.x & 63;
    int g = lane >> 3, t = lane & 7;
    unsigned cB = (unsigned)t * 12;
    int j0 = startA[wid];
    int deg = degA[wid];
    unsigned rowB = (unsigned)csr_src[j0 + min(lane, deg - 1)] * 96u;
    const char* xlb = (const char*)xl2;
    f32x2 xrp[3];
    {
        U3 raw = *(const U3*)((const char*)xr2 + (unsigned)wid * 96u + cB);
        xrp[0] = unpk2(raw.x); xrp[1] = unpk2(raw.y); xrp[2] = unpk2(raw.z);
    }
    int c = t * 6;
    f32x2 a06[3];
    float a04[6];
#pragma unroll
    for (int k = 0; k < 6; k++) {
        float av = (c + k < CLS) ? a2[c + k] : 0.f;
        a04[k] = av * C04;
        if (k & 1) a06[k >> 1].y = av * C06; else a06[k >> 1].x = av * C06;
    }
    L2S st; st.s = 0.f;
    f32x2 z2 = {0.f, 0.f};
#pragma unroll
    for (int k = 0; k < 3; k++) st.acc[k] = z2;
    int nb = (deg + 7) >> 3;      // 8 edges per batch, one per 8-lane group
    U3 u[4];
#pragma unroll
    for (int i = 0; i < 2; i++) {
        int pp = min(i * 8 + g, deg - 1);     // <= 31, shfl-safe
        u[i] = *(const U3*)(xlb + (__shfl(rowB, pp) + cB));
    }
    if (nb > 2) {
#pragma unroll
        for (int i = 2; i < 4; i++) {
            int pp = min(i * 8 + g, deg - 1); // <= 31, shfl-safe
            u[i] = *(const U3*)(xlb + (__shfl(rowB, pp) + cB));
        }
    }
    l2_consume(u[0], g < deg, xrp, a06, a04, st);
    if (nb > 1) l2_consume(u[1], 8 + g < deg, xrp, a06, a04, st);
    if (nb > 2) {
        l2_consume(u[2], 16 + g < deg, xrp, a06, a04, st);
        if (nb > 3) l2_consume(u[3], 24 + g < deg, xrp, a06, a04, st);
        // deg > 32: rare serial fallback (handles deg > 64 too).
        for (int b = 4; b < nb; b++) {
            int p = b * 8 + g;
            bool valid = p < deg;
            int pp = valid ? p : deg - 1;
            unsigned o = __shfl(rowB, min(pp, 63)) + cB;
            if (pp >= 64) o = (unsigned)csr_src[j0 + pp] * 96u + cB;
            U3 uu = *(const U3*)(xlb + o);
            l2_consume(uu, valid, xrp, a06, a04, st);
        }
    }
#pragma unroll
    for (int d = 8; d < 64; d <<= 1) {
        st.s += __shfl_xor(st.s, d);
#pragma unroll
        for (int k = 0; k < 3; k++) {
            st.acc[k].x += __shfl_xor(st.acc[k].x, d);
            st.acc[k].y += __shfl_xor(st.acc[k].y, d);
        }
    }
    float inv = 1.f / st.s;
    float q[6];
    float mx = -3e38f;
#pragma unroll
    for (int k = 0; k < 6; k++) {
        bool val = (c + k < CLS);
        float av = (k & 1) ? st.acc[k >> 1].y : st.acc[k >> 1].x;
        float xv = (k & 1) ? xrp[k >> 1].y : xrp[k >> 1].x;
        q[k] = val ? (av * inv - xv + b2[c + k]) : -3e38f;
        mx = fmaxf(mx, q[k]);
    }
    mx = fmaxf(mx, __shfl_xor(mx, 1));
    mx = fmaxf(mx, __shfl_xor(mx, 2));
    mx = fmaxf(mx, __shfl_xor(mx, 4));
    float se = 0.f;
#pragma unroll
    for (int k = 0; k < 6; k++) if (c + k < CLS) se += __expf(q[k] - mx);
    se += __shfl_xor(se, 1);
    se += __shfl_xor(se, 2);
    se += __shfl_xor(se, 4);
    float ls = mx + __logf(se);
    if (g == 0) {
        float* o = out + (size_t)wid * CLS + c;
#pragma unroll
        for (int k = 0; k < 6; k++)
            if (c + k < CLS) o[k] = q[k] - ls;
    }
}

extern "C" void kernel_launch(void* const* d_in, const int* in_sizes, int n_in,
                              void* d_out, int out_size, void* d_ws, size_t ws_size,
                              hipStream_t stream) {
    const float* x   = (const float*)d_in[0];
    const int*   ei  = (const int*)d_in[1];
    const float* w1l = (const float*)d_in[2];
    const float* w1r = (const float*)d_in[3];
    const float* a1  = (const float*)d_in[4];
    const float* b1  = (const float*)d_in[5];
    const float* w2l = (const float*)d_in[6];
    const float* w2r = (const float*)d_in[7];
    const float* a2  = (const float*)d_in[8];
    const float* b2  = (const float*)d_in[9];
    float* out = (float*)d_out;

    // Workspace layout (total ~52.1 MB):
    char* base = (char*)d_ws;
    int*   startA  = (int*)(base + 0);             //   200,704 B (NPAD)
    int*   degA    = (int*)(base + 200704);        //   200,704 B
    int*   cursor  = (int*)(base + 401408);        //   200,704 B
    int*   csr_src = (int*)(base + 602112);        //  3,400,000 B (ETOT)
    bf16*  xl1     = (bf16*)(base + 4002112);      // 25,600,000 B (xl1|xr1)
    bf16*  hb      = (bf16*)(base + 29602112);     // 12,800,000 B
    bf16*  xl2p    = (bf16*)(base + 42402112);     //  9,600,000 B (xl2p|xr2p, stride 48)
    bf16*  wT1     = (bf16*)(base + 52002112);     //     65,536 B
    bf16*  wT2     = (bf16*)(base + 52067648);     //     24,576 B
    bf16* xr1  = xl1 + (size_t)NN * 128;
    bf16* xr2p = xl2p + (size_t)NN * CLSP;

    prep<<<PREPB, 256, 0, stream>>>(w1l, w1r, w2l, w2r, wT1, wT2, degA);
    gemm1_count<<<GB1 + CNTB, 256, 0, stream>>>(x, wT1, xl1, xr1, ei, degA);
    scan_deg<<<1, 256, 0, stream>>>(degA, startA, cursor);
    scatter<<<SCB, 256, 0, stream>>>(ei, cursor, csr_src);
    node_l1<<<(NHALF * 64) / 256, 256, 0, stream>>>(startA, degA, csr_src, xl1, xr1, a1, b1, hb, 0);
    node_l1<<<(NHALF * 64) / 256, 256, 0, stream>>>(startA, degA, csr_src, xl1, xr1, a1, b1, hb, NHALF);
    gemm2<<<GB1, 256, 0, stream>>>(hb, wT2, xl2p, xr2p);
    node_l2<<<(NHALF * 64) / 256, 256, 0, stream>>>(startA, degA, csr_src, xl2p, xr2p, a2, b2, out, 0);
    node_l2<<<(NHALF * 64) / 256, 256, 0, stream>>>(startA, degA, csr_src, xl2p, xr2p, a2, b2, out, NHALF);
}

// Round 6
// 248.300 us; speedup vs baseline: 1.2644x; 1.2644x over previous
//
#include <hip/hip_runtime.h>
#include <hip/hip_bf16.h>
#include <math.h>

#define NN 50000
#define NE 800000
#define ETOT (NE + NN)      // 850000, self-loops appended after edges
#define CLS 40
#define CLSP 48             // layer-2 channels padded to 48
#define NEG 0.2f
#define MTILES (NN / 16)    // 3125 exact
#define GB1 ((MTILES + 3) / 4)   // 782 gemm blocks
#define PREPB 176           // prep blocks: ceil(45056/256)
#define NBUCK 196           // ceil(50000/256) dst buckets of 256 nodes
#define BCAP 8192           // per-bucket capacity (mean 4352, sd ~64)
#define EB 4096             // edges per edge_scatter block
#define KAB ((ETOT + EB - 1) / EB)   // 208
#define NHALF (NN / 2)      // 25000: node kernels split into two dispatches

#define L2E 1.44269504088896f
#define C06 (0.6f * L2E)
#define C04 (0.4f * L2E)

typedef __hip_bfloat16 bf16;
typedef __attribute__((ext_vector_type(8))) __bf16 bf16x8;
typedef __attribute__((ext_vector_type(4))) float f32x4;
typedef __attribute__((ext_vector_type(2))) float f32x2;
struct U3 { unsigned x, y, z; };   // 12B, 4-aligned

__device__ __forceinline__ bf16x8 cvt8(f32x4 a, f32x4 b) {
    bf16x8 r;
    r[0] = (__bf16)a[0]; r[1] = (__bf16)a[1]; r[2] = (__bf16)a[2]; r[3] = (__bf16)a[3];
    r[4] = (__bf16)b[0]; r[5] = (__bf16)b[1]; r[6] = (__bf16)b[2]; r[7] = (__bf16)b[3];
    return r;
}
// 2 packed bf16 (one u32) -> f32x2 (register pair feeding v_pk_* ops)
__device__ __forceinline__ f32x2 unpk2(unsigned u) {
    f32x2 r;
    r.x = __uint_as_float(u << 16);
    r.y = __uint_as_float(u & 0xffff0000u);
    return r;
}

// 256-entry exclusive scan in LDS (4 waves). Returns exclusive prefix of v.
__device__ __forceinline__ unsigned scan256(unsigned v, unsigned* wsum) {
    int t = threadIdx.x;
    int lane = t & 63, w = t >> 6;
    unsigned inc = v;
#pragma unroll
    for (int d = 1; d < 64; d <<= 1) {
        unsigned x = __shfl_up(inc, d);
        if (lane >= d) inc += x;
    }
    if (lane == 63) wsum[w] = inc;
    __syncthreads();
    unsigned woff = 0;
#pragma unroll
    for (int i = 0; i < 4; i++) woff += (i < w) ? wsum[i] : 0;
    return woff + inc - v;
}

// ---- K1: weight prep (fp32->bf16 transposed) + zero bucket cursors. ----
__global__ __launch_bounds__(256) void prep(
        const float* __restrict__ w1l, const float* __restrict__ w1r,
        const float* __restrict__ w2l, const float* __restrict__ w2r,
        bf16* __restrict__ wT1, bf16* __restrict__ wT2,
        int* __restrict__ bcursor) {
    int t = blockIdx.x * 256 + threadIdx.x;
    if (t < NBUCK) bcursor[t] = 0;
    if (t < 2 * 128 * 128) {
        int m = t >> 14;
        int idx = t & 16383;
        int n = idx >> 7, k = idx & 127;
        const float* w = m ? w1r : w1l;
        wT1[t] = __float2bfloat16(w[k * 128 + n]);
    } else if (t < 2 * 128 * 128 + 2 * CLSP * 128) {
        int u = t - 2 * 128 * 128;
        int m = u / (CLSP * 128);
        int idx = u % (CLSP * 128);
        int n = idx >> 7, k = idx & 127;
        const float* w = m ? w2r : w2l;
        wT2[u] = __float2bfloat16((n < CLS) ? w[k * CLS + n] : 0.0f);
    }
}

// ---- K2a: GEMM1 dual (xl1,xr1 = x @ w1{l,r}). No LDS -> high occupancy. ----
__global__ __launch_bounds__(256) void gemm1(
        const float* __restrict__ x, const bf16* __restrict__ wT,
        bf16* __restrict__ outL, bf16* __restrict__ outR) {
    int wave = threadIdx.x >> 6;
    int lane = threadIdx.x & 63;
    int tile = blockIdx.x * 4 + wave;
    if (tile >= MTILES) return;
    const bf16* wl = wT;
    const bf16* wr = wT + 128 * 128;
    int row0 = tile * 16;
    int l16 = lane & 15, quad = lane >> 4;
    f32x4 z = {0.f, 0.f, 0.f, 0.f};
    f32x4 accl[8], accr[8];
#pragma unroll
    for (int i = 0; i < 8; i++) { accl[i] = z; accr[i] = z; }
    const float* xrow = x + (size_t)(row0 + l16) * 128 + quad * 8;
#pragma unroll
    for (int k0 = 0; k0 < 128; k0 += 32) {
        f32x4 a0 = *reinterpret_cast<const f32x4*>(xrow + k0);
        f32x4 a1v = *reinterpret_cast<const f32x4*>(xrow + k0 + 4);
        bf16x8 a = cvt8(a0, a1v);
#pragma unroll
        for (int ct = 0; ct < 8; ct++) {
            bf16x8 bl = *reinterpret_cast<const bf16x8*>(wl + (ct * 16 + l16) * 128 + k0 + quad * 8);
            bf16x8 br = *reinterpret_cast<const bf16x8*>(wr + (ct * 16 + l16) * 128 + k0 + quad * 8);
            accl[ct] = __builtin_amdgcn_mfma_f32_16x16x32_bf16(a, bl, accl[ct], 0, 0, 0);
            accr[ct] = __builtin_amdgcn_mfma_f32_16x16x32_bf16(a, br, accr[ct], 0, 0, 0);
        }
    }
#pragma unroll
    for (int ct = 0; ct < 8; ct++)
#pragma unroll
        for (int r = 0; r < 4; r++) {
            size_t o = (size_t)(row0 + quad * 4 + r) * 128 + ct * 16 + l16;
            outL[o] = __float2bfloat16(accl[ct][r]);
            outR[o] = __float2bfloat16(accr[ct][r]);
        }
}

// ---- K2b: LDS-binned edge scatter into bucket-strided tmp. ----
__global__ __launch_bounds__(256) void edge_scatter(
        const int* __restrict__ ei, int* __restrict__ bcursor,
        uint2* __restrict__ tmp) {
    __shared__ unsigned hist[256];
    __shared__ unsigned lstart[256];
    __shared__ unsigned lcur[256];
    __shared__ unsigned gbase[256];
    __shared__ unsigned wsum[4];
    __shared__ uint2 binned[EB];
    __shared__ unsigned target[EB];
    int t = threadIdx.x;
    int e0 = blockIdx.x * EB;
    hist[t] = 0;
    __syncthreads();
    int srcs[16], dsts[16];
#pragma unroll
    for (int i = 0; i < 16; i++) {
        int e = e0 + i * 256 + t;
        if (e < ETOT) {
            int s, d;
            if (e < NE) { s = ei[e]; d = ei[NE + e]; }
            else        { s = d = e - NE; }
            srcs[i] = s; dsts[i] = d;
            atomicAdd(&hist[d >> 8], 1u);
        } else dsts[i] = -1;
    }
    __syncthreads();
    unsigned v = hist[t];
    unsigned excl = scan256(v, wsum);
    lstart[t] = excl;
    lcur[t] = 0;
    __syncthreads();
    if (t < NBUCK && v > 0)
        gbase[t] = (unsigned)atomicAdd(&bcursor[t], (int)v) + (unsigned)t * BCAP;
    __syncthreads();
#pragma unroll
    for (int i = 0; i < 16; i++) {
        int d = dsts[i];
        if (d >= 0) {
            int bk = d >> 8;
            unsigned p = atomicAdd(&lcur[bk], 1u);
            unsigned slot = lstart[bk] + p;
            binned[slot] = make_uint2((unsigned)srcs[i], (unsigned)d);
            target[slot] = gbase[bk] + p;
        }
    }
    __syncthreads();
    int tot = min(EB, ETOT - e0);
    for (int s = t; s < tot; s += 256)
        tmp[target[s]] = binned[s];
}

// ---- KB: per-bucket node sort -> csr_src + start/deg. One block per bucket. ----
// Scattered permutation happens in LDS (vals[BCAP]); global csr write is
// fully coalesced streaming.
__global__ __launch_bounds__(256) void bucket_sort(const int* __restrict__ bcursor,
                                                   const uint2* __restrict__ tmp,
                                                   int* __restrict__ csr_src,
                                                   int* __restrict__ startA,
                                                   int* __restrict__ degA) {
    __shared__ unsigned hist[256];
    __shared__ unsigned lcur[256];
    __shared__ unsigned wsum[4];
    __shared__ int vals[BCAP];          // 32 KB LDS staging
    int b = blockIdx.x, t = threadIdx.x;
    int cnt = bcursor[b];
    hist[t] = 0;
    __syncthreads();
    const uint2* seg = tmp + (size_t)b * BCAP;
    for (int s = t; s < cnt; s += 256)
        atomicAdd(&hist[seg[s].y & 255], 1u);
    __syncthreads();
    unsigned v = hist[t];
    unsigned excl = scan256(v, wsum);
    lcur[t] = excl;
    int node = b * 256 + t;
    if (node < NN) {
        startA[node] = b * BCAP + (int)excl;
        degA[node] = (int)v;
    }
    __syncthreads();
    for (int s = t; s < cnt; s += 256) {
        uint2 p = seg[s];                       // L2-hot re-read
        unsigned pos = atomicAdd(&lcur[p.y & 255], 1u);
        vals[pos] = (int)p.x;                   // scattered write stays in LDS
    }
    __syncthreads();
    int* cbase = csr_src + (size_t)b * BCAP;
    for (int s = t; s < cnt; s += 256)
        cbase[s] = vals[s];                     // coalesced global stream
}

// ---- K5: layer 1 fused. One wave/node, 16 lanes/edge, up to 32 edges in flight. ----
// Packed-fp32 math: leaky(v)=0.6v+0.4|v|; logit uses v_pk_fma for the 0.6-dot
// and scalar v_fma with free |t| modifier for the 0.4-dot; log2e prefolded
// into the coefficients so exp is a single v_exp_f32. The accumulator sums
// w*t (t = xl[src]+xr[dst]); epilogue corrects acc/s - xr = sum(w*xl)/s.
struct L1S { float s; f32x2 acc[4]; };
__device__ __forceinline__ void l1_consume(uint4 u, bool valid, const f32x2* xrp,
                                           const f32x2* a06, const float* a04, L1S& st) {
    f32x2 t0 = unpk2(u.x) + xrp[0];
    f32x2 t1 = unpk2(u.y) + xrp[1];
    f32x2 t2 = unpk2(u.z) + xrp[2];
    f32x2 t3 = unpk2(u.w) + xrp[3];
    f32x2 ep = t0 * a06[0];
    ep = __builtin_elementwise_fma(t1, a06[1], ep);
    ep = __builtin_elementwise_fma(t2, a06[2], ep);
    ep = __builtin_elementwise_fma(t3, a06[3], ep);
    float e0 = fmaf(a04[1], fabsf(t0.y), a04[0] * fabsf(t0.x));
    e0 = fmaf(a04[2], fabsf(t1.x), e0);
    e0 = fmaf(a04[3], fabsf(t1.y), e0);
    float e1 = fmaf(a04[5], fabsf(t2.y), a04[4] * fabsf(t2.x));
    e1 = fmaf(a04[6], fabsf(t3.x), e1);
    e1 = fmaf(a04[7], fabsf(t3.y), e1);
    float e = (ep.x + ep.y) + (e0 + e1);
    e += __shfl_xor(e, 1);
    e += __shfl_xor(e, 2);          // per-head logit (4-lane quad)
    float w = valid ? __builtin_amdgcn_exp2f(e) : 0.f;
    st.s += w;
    f32x2 wv = {w, w};
    st.acc[0] = __builtin_elementwise_fma(wv, t0, st.acc[0]);
    st.acc[1] = __builtin_elementwise_fma(wv, t1, st.acc[1]);
    st.acc[2] = __builtin_elementwise_fma(wv, t2, st.acc[2]);
    st.acc[3] = __builtin_elementwise_fma(wv, t3, st.acc[3]);
}

__global__ __launch_bounds__(256) void node_l1(const int* __restrict__ startA,
                                               const int* __restrict__ degA,
                                               const int* __restrict__ csr_src,
                                               const bf16* __restrict__ xl,
                                               const bf16* __restrict__ xr,
                                               const float* __restrict__ a1,
                                               const float* __restrict__ b1,
                                               bf16* __restrict__ hb,
                                               int nbase) {
    int wid = nbase + ((blockIdx.x * 256 + threadIdx.x) >> 6);
    int lane = threadIdx.x & 63;
    int g = lane >> 4, t = lane & 15;
    unsigned cB = (unsigned)t * 16;
    int j0 = startA[wid];
    int deg = degA[wid];
    unsigned rowB = (unsigned)csr_src[j0 + min(lane, deg - 1)] << 8;
    const char* xlb = (const char*)xl;
    f32x2 xrp[4];
    {
        uint4 raw = *(const uint4*)((const char*)xr + ((unsigned)wid << 8) + cB);
        xrp[0] = unpk2(raw.x); xrp[1] = unpk2(raw.y);
        xrp[2] = unpk2(raw.z); xrp[3] = unpk2(raw.w);
    }
    f32x2 a06[4];
    float a04[8];
    {
        f32x4 lo = *reinterpret_cast<const f32x4*>(a1 + t * 8);
        f32x4 hi = *reinterpret_cast<const f32x4*>(a1 + t * 8 + 4);
        float af[8];
#pragma unroll
        for (int k = 0; k < 4; k++) { af[k] = lo[k]; af[k + 4] = hi[k]; }
#pragma unroll
        for (int j = 0; j < 4; j++) {
            a06[j].x = af[2 * j] * C06;
            a06[j].y = af[2 * j + 1] * C06;
        }
#pragma unroll
        for (int k = 0; k < 8; k++) a04[k] = af[k] * C04;
    }
    L1S st; st.s = 0.f;
    f32x2 z2 = {0.f, 0.f};
#pragma unroll
    for (int k = 0; k < 4; k++) st.acc[k] = z2;
    int nb = (deg + 3) >> 2;      // 4 edges per batch, one per 16-lane group
    uint4 u[8];
    // Round 1: batches 0-3 (edges 0-15), addresses clamped so loads are
    // always valid; overshoot slots re-read the last row (L1-hot).
#pragma unroll
    for (int i = 0; i < 4; i++) {
        int pp = min(i * 4 + g, deg - 1);     // <= 31, shfl-safe
        u[i] = *(const uint4*)(xlb + (__shfl(rowB, pp) + cB));
    }
    if (nb > 4) {
        // Round 2 loads issue BEFORE any consume: up to 32 edges in flight.
#pragma unroll
        for (int i = 4; i < 8; i++) {
            int pp = min(i * 4 + g, deg - 1); // <= 31, shfl-safe
            u[i] = *(const uint4*)(xlb + (__shfl(rowB, pp) + cB));
        }
    }
    l1_consume(u[0], g < deg, xrp, a06, a04, st);
    if (nb > 1) l1_consume(u[1], 4 + g < deg, xrp, a06, a04, st);
    if (nb > 2) l1_consume(u[2], 8 + g < deg, xrp, a06, a04, st);
    if (nb > 3) l1_consume(u[3], 12 + g < deg, xrp, a06, a04, st);
    if (nb > 4) {
        l1_consume(u[4], 16 + g < deg, xrp, a06, a04, st);
        if (nb > 5) l1_consume(u[5], 20 + g < deg, xrp, a06, a04, st);
        if (nb > 6) l1_consume(u[6], 24 + g < deg, xrp, a06, a04, st);
        if (nb > 7) l1_consume(u[7], 28 + g < deg, xrp, a06, a04, st);
        // deg > 32: rare serial fallback (handles deg > 64 too).
        for (int b = 8; b < nb; b++) {
            int p = b * 4 + g;
            bool valid = p < deg;
            int pp = valid ? p : deg - 1;
            unsigned o = __shfl(rowB, min(pp, 63)) + cB;
            if (pp >= 64) o = (((unsigned)csr_src[j0 + pp]) << 8) + cB;
            uint4 uu = *(const uint4*)(xlb + o);
            l1_consume(uu, valid, xrp, a06, a04, st);
        }
    }
#pragma unroll
    for (int d = 16; d < 64; d <<= 1) {
        st.s += __shfl_xor(st.s, d);
#pragma unroll
        for (int k = 0; k < 4; k++) {
            st.acc[k].x += __shfl_xor(st.acc[k].x, d);
            st.acc[k].y += __shfl_xor(st.acc[k].y, d);
        }
    }
    if (g == 0) {
        float inv = 1.f / st.s;
        unsigned pk[4];
#pragma unroll
        for (int k = 0; k < 4; k++) {
            float o0 = st.acc[k].x * inv - xrp[k].x + b1[t * 8 + 2 * k];
            float o1 = st.acc[k].y * inv - xrp[k].y + b1[t * 8 + 2 * k + 1];
            o0 = o0 > 0.f ? o0 : __expf(o0) - 1.f;
            o1 = o1 > 0.f ? o1 : __expf(o1) - 1.f;
            bf16 r0 = __float2bfloat16(o0), r1 = __float2bfloat16(o1);
            pk[k] = (unsigned)*reinterpret_cast<unsigned short*>(&r0) |
                    ((unsigned)*reinterpret_cast<unsigned short*>(&r1) << 16);
        }
        uint4 w4 = {pk[0], pk[1], pk[2], pk[3]};
        *(uint4*)((char*)hb + ((unsigned)wid << 8) + cB) = w4;
    }
}

// ---- K6: GEMM2 dual: xl2p/xr2p = h @ w2{l,r}(128x48 zero-padded), stride 48. ----
__global__ __launch_bounds__(256) void gemm2(const bf16* __restrict__ h,
                                             const bf16* __restrict__ wT,
                                             bf16* __restrict__ outL,
                                             bf16* __restrict__ outR) {
    int wave = threadIdx.x >> 6;
    int lane = threadIdx.x & 63;
    int tile = blockIdx.x * 4 + wave;
    if (tile >= MTILES) return;
    const bf16* wl = wT;
    const bf16* wr = wT + CLSP * 128;
    int row0 = tile * 16;
    int l16 = lane & 15, quad = lane >> 4;
    f32x4 z = {0.f, 0.f, 0.f, 0.f};
    f32x4 accl[3], accr[3];
#pragma unroll
    for (int i = 0; i < 3; i++) { accl[i] = z; accr[i] = z; }
    const bf16* hrow = h + (size_t)(row0 + l16) * 128 + quad * 8;
#pragma unroll
    for (int k0 = 0; k0 < 128; k0 += 32) {
        bf16x8 a = *reinterpret_cast<const bf16x8*>(hrow + k0);
#pragma unroll
        for (int ct = 0; ct < 3; ct++) {
            bf16x8 bl = *reinterpret_cast<const bf16x8*>(wl + (ct * 16 + l16) * 128 + k0 + quad * 8);
            bf16x8 br = *reinterpret_cast<const bf16x8*>(wr + (ct * 16 + l16) * 128 + k0 + quad * 8);
            accl[ct] = __builtin_amdgcn_mfma_f32_16x16x32_bf16(a, bl, accl[ct], 0, 0, 0);
            accr[ct] = __builtin_amdgcn_mfma_f32_16x16x32_bf16(a, br, accr[ct], 0, 0, 0);
        }
    }
#pragma unroll
    for (int ct = 0; ct < 3; ct++)
#pragma unroll
        for (int r = 0; r < 4; r++) {
            size_t o = (size_t)(row0 + quad * 4 + r) * CLSP + ct * 16 + l16;
            outL[o] = __float2bfloat16(accl[ct][r]);
            outR[o] = __float2bfloat16(accr[ct][r]);
        }
}

// ---- K7: layer 2 fused. One wave/node, 8 lanes/edge, up to 32 edges in flight. ----
struct L2S { float s; f32x2 acc[3]; };
__device__ __forceinline__ void l2_consume(U3 u, bool valid, const f32x2* xrp,
                                           const f32x2* a06, const float* a04, L2S& st) {
    f32x2 t0 = unpk2(u.x) + xrp[0];
    f32x2 t1 = unpk2(u.y) + xrp[1];
    f32x2 t2 = unpk2(u.z) + xrp[2];
    f32x2 ep = t0 * a06[0];
    ep = __builtin_elementwise_fma(t1, a06[1], ep);
    ep = __builtin_elementwise_fma(t2, a06[2], ep);
    float es = fmaf(a04[1], fabsf(t0.y), a04[0] * fabsf(t0.x));
    es = fmaf(a04[2], fabsf(t1.x), es);
    es = fmaf(a04[3], fabsf(t1.y), es);
    es = fmaf(a04[4], fabsf(t2.x), es);
    es = fmaf(a04[5], fabsf(t2.y), es);
    float e = (ep.x + ep.y) + es;
    e += __shfl_xor(e, 1);
    e += __shfl_xor(e, 2);
    e += __shfl_xor(e, 4);          // full 48-ch logit (8-lane group)
    float w = valid ? __builtin_amdgcn_exp2f(e) : 0.f;
    st.s += w;
    f32x2 wv = {w, w};
    st.acc[0] = __builtin_elementwise_fma(wv, t0, st.acc[0]);
    st.acc[1] = __builtin_elementwise_fma(wv, t1, st.acc[1]);
    st.acc[2] = __builtin_elementwise_fma(wv, t2, st.acc[2]);
}

__global__ __launch_bounds__(256) void node_l2(const int* __restrict__ startA,
                                               const int* __restrict__ degA,
                                               const int* __restrict__ csr_src,
                                               const bf16* __restrict__ xl2,
                                               const bf16* __restrict__ xr2,
                                               const float* __restrict__ a2,
                                               const float* __restrict__ b2,
                                               float* __restrict__ out,
                                               int nbase) {
    int wid = nbase + ((blockIdx.x * 256 + threadIdx.x) >> 6);
    int lane = threadIdx.x & 63;
    int g = lane >> 3, t = lane & 7;
    unsigned cB = (unsigned)t * 12;
    int j0 = startA[wid];
    int deg = degA[wid];
    unsigned rowB = (unsigned)csr_src[j0 + min(lane, deg - 1)] * 96u;
    const char* xlb = (const char*)xl2;
    f32x2 xrp[3];
    {
        U3 raw = *(const U3*)((const char*)xr2 + (unsigned)wid * 96u + cB);
        xrp[0] = unpk2(raw.x); xrp[1] = unpk2(raw.y); xrp[2] = unpk2(raw.z);
    }
    int c = t * 6;
    f32x2 a06[3];
    float a04[6];
#pragma unroll
    for (int k = 0; k < 6; k++) {
        float av = (c + k < CLS) ? a2[c + k] : 0.f;
        a04[k] = av * C04;
        if (k & 1) a06[k >> 1].y = av * C06; else a06[k >> 1].x = av * C06;
    }
    L2S st; st.s = 0.f;
    f32x2 z2 = {0.f, 0.f};
#pragma unroll
    for (int k = 0; k < 3; k++) st.acc[k] = z2;
    int nb = (deg + 7) >> 3;      // 8 edges per batch, one per 8-lane group
    U3 u[4];
#pragma unroll
    for (int i = 0; i < 2; i++) {
        int pp = min(i * 8 + g, deg - 1);     // <= 31, shfl-safe
        u[i] = *(const U3*)(xlb + (__shfl(rowB, pp) + cB));
    }
    if (nb > 2) {
#pragma unroll
        for (int i = 2; i < 4; i++) {
            int pp = min(i * 8 + g, deg - 1); // <= 31, shfl-safe
            u[i] = *(const U3*)(xlb + (__shfl(rowB, pp) + cB));
        }
    }
    l2_consume(u[0], g < deg, xrp, a06, a04, st);
    if (nb > 1) l2_consume(u[1], 8 + g < deg, xrp, a06, a04, st);
    if (nb > 2) {
        l2_consume(u[2], 16 + g < deg, xrp, a06, a04, st);
        if (nb > 3) l2_consume(u[3], 24 + g < deg, xrp, a06, a04, st);
        // deg > 32: rare serial fallback (handles deg > 64 too).
        for (int b = 4; b < nb; b++) {
            int p = b * 8 + g;
            bool valid = p < deg;
            int pp = valid ? p : deg - 1;
            unsigned o = __shfl(rowB, min(pp, 63)) + cB;
            if (pp >= 64) o = (unsigned)csr_src[j0 + pp] * 96u + cB;
            U3 uu = *(const U3*)(xlb + o);
            l2_consume(uu, valid, xrp, a06, a04, st);
        }
    }
#pragma unroll
    for (int d = 8; d < 64; d <<= 1) {
        st.s += __shfl_xor(st.s, d);
#pragma unroll
        for (int k = 0; k < 3; k++) {
            st.acc[k].x += __shfl_xor(st.acc[k].x, d);
            st.acc[k].y += __shfl_xor(st.acc[k].y, d);
        }
    }
    float inv = 1.f / st.s;
    float q[6];
    float mx = -3e38f;
#pragma unroll
    for (int k = 0; k < 6; k++) {
        bool val = (c + k < CLS);
        float av = (k & 1) ? st.acc[k >> 1].y : st.acc[k >> 1].x;
        float xv = (k & 1) ? xrp[k >> 1].y : xrp[k >> 1].x;
        q[k] = val ? (av * inv - xv + b2[c + k]) : -3e38f;
        mx = fmaxf(mx, q[k]);
    }
    mx = fmaxf(mx, __shfl_xor(mx, 1));
    mx = fmaxf(mx, __shfl_xor(mx, 2));
    mx = fmaxf(mx, __shfl_xor(mx, 4));
    float se = 0.f;
#pragma unroll
    for (int k = 0; k < 6; k++) if (c + k < CLS) se += __expf(q[k] - mx);
    se += __shfl_xor(se, 1);
    se += __shfl_xor(se, 2);
    se += __shfl_xor(se, 4);
    float ls = mx + __logf(se);
    if (g == 0) {
        float* o = out + (size_t)wid * CLS + c;
#pragma unroll
        for (int k = 0; k < 6; k++)
            if (c + k < CLS) o[k] = q[k] - ls;
    }
}

extern "C" void kernel_launch(void* const* d_in, const int* in_sizes, int n_in,
                              void* d_out, int out_size, void* d_ws, size_t ws_size,
                              hipStream_t stream) {
    const float* x   = (const float*)d_in[0];
    const int*   ei  = (const int*)d_in[1];
    const float* w1l = (const float*)d_in[2];
    const float* w1r = (const float*)d_in[3];
    const float* a1  = (const float*)d_in[4];
    const float* b1  = (const float*)d_in[5];
    const float* w2l = (const float*)d_in[6];
    const float* w2r = (const float*)d_in[7];
    const float* a2  = (const float*)d_in[8];
    const float* b2  = (const float*)d_in[9];
    float* out = (float*)d_out;

    // Workspace layout (total ~67.8 MB):
    char* base = (char*)d_ws;
    int*   bcursor = (int*)(base + 0);             //       784 B (zeroed by prep)
    int*   startA  = (int*)(base + 1024);          //   200,000 B
    int*   degA    = (int*)(base + 201024);        //   200,000 B
    uint2* tmp     = (uint2*)(base + 401024);      // 12,845,056 B (NBUCK*BCAP*8)
    int*   csr_src = (int*)(base + 13246080);      //  6,422,528 B (NBUCK*BCAP*4)
    bf16*  xl1     = (bf16*)(base + 19668608);     // 25,600,000 B (xl1|xr1)
    bf16*  hb      = (bf16*)(base + 45268608);     // 12,800,000 B
    bf16*  xl2p    = (bf16*)(base + 58068608);     //  9,600,000 B (xl2p|xr2p, stride 48)
    bf16*  wT1     = (bf16*)(base + 67668608);     //     65,536 B
    bf16*  wT2     = (bf16*)(base + 67734144);     //     24,576 B
    bf16* xr1  = xl1 + (size_t)NN * 128;
    bf16* xr2p = xl2p + (size_t)NN * CLSP;

    prep<<<PREPB, 256, 0, stream>>>(w1l, w1r, w2l, w2r, wT1, wT2, bcursor);
    gemm1<<<GB1, 256, 0, stream>>>(x, wT1, xl1, xr1);
    edge_scatter<<<KAB, 256, 0, stream>>>(ei, bcursor, tmp);
    bucket_sort<<<NBUCK, 256, 0, stream>>>(bcursor, tmp, csr_src, startA, degA);
    node_l1<<<(NHALF * 64) / 256, 256, 0, stream>>>(startA, degA, csr_src, xl1, xr1, a1, b1, hb, 0);
    node_l1<<<(NHALF * 64) / 256, 256, 0, stream>>>(startA, degA, csr_src, xl1, xr1, a1, b1, hb, NHALF);
    gemm2<<<GB1, 256, 0, stream>>>(hb, wT2, xl2p, xr2p);
    node_l2<<<(NHALF * 64) / 256, 256, 0, stream>>>(startA, degA, csr_src, xl2p, xr2p, a2, b2, out, 0);
    node_l2<<<(NHALF * 64) / 256, 256, 0, stream>>>(startA, degA, csr_src, xl2p, xr2p, a2, b2, out, NHALF);
}

// Round 7
// 203.608 us; speedup vs baseline: 1.5419x; 1.2195x over previous
//
#include <hip/hip_runtime.h>
#include <hip/hip_bf16.h>
#include <math.h>

#define NN 50000
#define NE 800000
#define ETOT (NE + NN)      // 850000, self-loops appended after edges
#define CLS 40
#define CLSP 48             // layer-2 channels padded to 48
#define NEG 0.2f
#define MTILES (NN / 16)    // 3125 exact
#define GB1 ((MTILES + 3) / 4)   // 782 gemm blocks
#define PREPB 176           // prep blocks: ceil(45056/256)
#define NBUCK 196           // ceil(50000/256) dst buckets of 256 nodes
#define BCAP 8192           // per-bucket capacity (mean 4352, sd ~64)
#define EB 4096             // edges per scatter block
#define KAB ((ETOT + EB - 1) / EB)   // 208

#define L2E 1.44269504088896f
#define C06 (0.6f * L2E)
#define C04 (0.4f * L2E)

typedef __hip_bfloat16 bf16;
typedef __attribute__((ext_vector_type(8))) __bf16 bf16x8;
typedef __attribute__((ext_vector_type(4))) float f32x4;
typedef __attribute__((ext_vector_type(2))) float f32x2;
struct U3 { unsigned x, y, z; };   // 12B, 4-aligned

__device__ __forceinline__ bf16x8 cvt8(f32x4 a, f32x4 b) {
    bf16x8 r;
    r[0] = (__bf16)a[0]; r[1] = (__bf16)a[1]; r[2] = (__bf16)a[2]; r[3] = (__bf16)a[3];
    r[4] = (__bf16)b[0]; r[5] = (__bf16)b[1]; r[6] = (__bf16)b[2]; r[7] = (__bf16)b[3];
    return r;
}
// 2 packed bf16 (one u32) -> f32x2 (register pair feeding v_pk_* ops)
__device__ __forceinline__ f32x2 unpk2(unsigned u) {
    f32x2 r;
    r.x = __uint_as_float(u << 16);
    r.y = __uint_as_float(u & 0xffff0000u);
    return r;
}

// 256-entry exclusive scan (4 waves). Returns exclusive prefix of v.
__device__ __forceinline__ unsigned scan256(unsigned v, unsigned* wsum) {
    int t = threadIdx.x;
    int lane = t & 63, w = t >> 6;
    unsigned inc = v;
#pragma unroll
    for (int d = 1; d < 64; d <<= 1) {
        unsigned x = __shfl_up(inc, d);
        if (lane >= d) inc += x;
    }
    if (lane == 63) wsum[w] = inc;
    __syncthreads();
    unsigned woff = 0;
#pragma unroll
    for (int i = 0; i < 4; i++) woff += (i < w) ? wsum[i] : 0;
    return woff + inc - v;
}

// ---- K1: weight prep (fp32->bf16 transposed) + zero bucket cursors. ----
__global__ __launch_bounds__(256) void prep(
        const float* __restrict__ w1l, const float* __restrict__ w1r,
        const float* __restrict__ w2l, const float* __restrict__ w2r,
        bf16* __restrict__ wT1, bf16* __restrict__ wT2,
        int* __restrict__ bcursor) {
    int t = blockIdx.x * 256 + threadIdx.x;
    if (t < NBUCK) bcursor[t] = 0;
    if (t < 2 * 128 * 128) {
        int m = t >> 14;
        int idx = t & 16383;
        int n = idx >> 7, k = idx & 127;
        const float* w = m ? w1r : w1l;
        wT1[t] = __float2bfloat16(w[k * 128 + n]);
    } else if (t < 2 * 128 * 128 + 2 * CLSP * 128) {
        int u = t - 2 * 128 * 128;
        int m = u / (CLSP * 128);
        int idx = u % (CLSP * 128);
        int n = idx >> 7, k = idx & 127;
        const float* w = m ? w2r : w2l;
        wT2[u] = __float2bfloat16((n < CLS) ? w[k * CLS + n] : 0.0f);
    }
}

// ---- K2: GEMM1 dual (LDS-staged weights) || LDS-binned edge scatter. ----
// One 64KB shared buffer, carved per branch. The gemm branch stages the full
// 2x128x128 bf16 weight table in LDS (XOR-swizzled, col ^= (row&7)<<4, applied
// on BOTH write and read) so the inner loop's 64 weight reads per wave are
// ds_read_b128 instead of serialized L1/L2 round-trips (the measured 42us
// latency wall of round 5).
__global__ __launch_bounds__(256) void gemm1_scatter(
        const float* __restrict__ x, const bf16* __restrict__ wT,
        bf16* __restrict__ outL, bf16* __restrict__ outR,
        const int* __restrict__ ei, int* __restrict__ bcursor,
        uint2* __restrict__ tmp) {
    __shared__ __align__(16) char smem[65536];
    if ((int)blockIdx.x < GB1) {
        // ---- stage weights: 4096 x 16B chunks, swizzled ----
        const uint4* wsrc = (const uint4*)wT;
#pragma unroll
        for (int i = 0; i < 16; i++) {
            int idx = i * 256 + threadIdx.x;
            uint4 v = wsrc[idx];
            int r = idx >> 4;                  // 256B row
            int c = (idx & 15) << 4;           // byte col
            *(uint4*)(smem + r * 256 + (c ^ ((r & 7) << 4))) = v;
        }
        __syncthreads();
        int wave = threadIdx.x >> 6;
        int lane = threadIdx.x & 63;
        int tile = blockIdx.x * 4 + wave;
        if (tile >= MTILES) return;
        int row0 = tile * 16;
        int l16 = lane & 15, quad = lane >> 4;
        f32x4 z = {0.f, 0.f, 0.f, 0.f};
        f32x4 accl[8], accr[8];
#pragma unroll
        for (int i = 0; i < 8; i++) { accl[i] = z; accr[i] = z; }
        const float* xrow = x + (size_t)(row0 + l16) * 128 + quad * 8;
#pragma unroll
        for (int k0 = 0; k0 < 128; k0 += 32) {
            f32x4 a0 = *reinterpret_cast<const f32x4*>(xrow + k0);
            f32x4 a1v = *reinterpret_cast<const f32x4*>(xrow + k0 + 4);
            bf16x8 a = cvt8(a0, a1v);
            int cc = k0 * 2 + quad * 16;       // byte col of this lane's 16B
#pragma unroll
            for (int ct = 0; ct < 8; ct++) {
                int rl = ct * 16 + l16;        // wl row
                int sw = cc ^ ((l16 & 7) << 4);
                bf16x8 bl = *(const bf16x8*)(smem + rl * 256 + sw);
                bf16x8 br = *(const bf16x8*)(smem + 32768 + rl * 256 + sw);
                accl[ct] = __builtin_amdgcn_mfma_f32_16x16x32_bf16(a, bl, accl[ct], 0, 0, 0);
                accr[ct] = __builtin_amdgcn_mfma_f32_16x16x32_bf16(a, br, accr[ct], 0, 0, 0);
            }
        }
#pragma unroll
        for (int ct = 0; ct < 8; ct++)
#pragma unroll
            for (int r = 0; r < 4; r++) {
                size_t o = (size_t)(row0 + quad * 4 + r) * 128 + ct * 16 + l16;
                outL[o] = __float2bfloat16(accl[ct][r]);
                outR[o] = __float2bfloat16(accr[ct][r]);
            }
    } else {
        unsigned* hist   = (unsigned*)smem;                 // 1KB
        unsigned* lstart = (unsigned*)(smem + 1024);        // 1KB
        unsigned* lcur   = (unsigned*)(smem + 2048);        // 1KB
        unsigned* gbase  = (unsigned*)(smem + 3072);        // 1KB
        unsigned* wsum   = (unsigned*)(smem + 4096);        // 16B
        uint2*    binned = (uint2*)(smem + 4608);           // 32KB
        unsigned* target = (unsigned*)(smem + 37376);       // 16KB
        int t = threadIdx.x;
        int e0 = ((int)blockIdx.x - GB1) * EB;
        hist[t] = 0;
        __syncthreads();
        int srcs[16], dsts[16];
#pragma unroll
        for (int i = 0; i < 16; i++) {
            int e = e0 + i * 256 + t;
            if (e < ETOT) {
                int s, d;
                if (e < NE) { s = ei[e]; d = ei[NE + e]; }
                else        { s = d = e - NE; }
                srcs[i] = s; dsts[i] = d;
                atomicAdd(&hist[d >> 8], 1u);
            } else dsts[i] = -1;
        }
        __syncthreads();
        unsigned v = hist[t];
        unsigned excl = scan256(v, wsum);
        lstart[t] = excl;
        lcur[t] = 0;
        __syncthreads();
        if (t < NBUCK && v > 0)
            gbase[t] = (unsigned)atomicAdd(&bcursor[t], (int)v) + (unsigned)t * BCAP;
        __syncthreads();
#pragma unroll
        for (int i = 0; i < 16; i++) {
            int d = dsts[i];
            if (d >= 0) {
                int bk = d >> 8;
                unsigned p = atomicAdd(&lcur[bk], 1u);
                unsigned slot = lstart[bk] + p;
                binned[slot] = make_uint2((unsigned)srcs[i], (unsigned)d);
                target[slot] = gbase[bk] + p;
            }
        }
        __syncthreads();
        int tot = min(EB, ETOT - e0);
        for (int s = t; s < tot; s += 256)
            tmp[target[s]] = binned[s];
    }
}

// ---- KB: per-bucket node sort -> csr_src + start/deg. One block per bucket. ----
// Scattered permutation stays in LDS; global csr write is coalesced streaming.
__global__ __launch_bounds__(256) void bucket_sort(const int* __restrict__ bcursor,
                                                   const uint2* __restrict__ tmp,
                                                   int* __restrict__ csr_src,
                                                   int* __restrict__ startA,
                                                   int* __restrict__ degA) {
    __shared__ unsigned hist[256];
    __shared__ unsigned lcur[256];
    __shared__ unsigned wsum[4];
    __shared__ int vals[BCAP];          // 32 KB LDS staging
    int b = blockIdx.x, t = threadIdx.x;
    int cnt = bcursor[b];
    hist[t] = 0;
    __syncthreads();
    const uint2* seg = tmp + (size_t)b * BCAP;
    for (int s = t; s < cnt; s += 256)
        atomicAdd(&hist[seg[s].y & 255], 1u);
    __syncthreads();
    unsigned v = hist[t];
    unsigned excl = scan256(v, wsum);
    lcur[t] = excl;
    int node = b * 256 + t;
    if (node < NN) {
        startA[node] = b * BCAP + (int)excl;
        degA[node] = (int)v;
    }
    __syncthreads();
    for (int s = t; s < cnt; s += 256) {
        uint2 p = seg[s];                       // L2-hot re-read
        unsigned pos = atomicAdd(&lcur[p.y & 255], 1u);
        vals[pos] = (int)p.x;                   // scattered write stays in LDS
    }
    __syncthreads();
    int* cbase = csr_src + (size_t)b * BCAP;
    for (int s = t; s < cnt; s += 256)
        cbase[s] = vals[s];                     // coalesced global stream
}

// ---- K5: layer 1 fused. One wave/node, 16 lanes/edge, up to 32 edges in flight. ----
struct L1S { float s; f32x2 acc[4]; };
__device__ __forceinline__ void l1_consume(uint4 u, bool valid, const f32x2* xrp,
                                           const f32x2* a06, const float* a04, L1S& st) {
    f32x2 t0 = unpk2(u.x) + xrp[0];
    f32x2 t1 = unpk2(u.y) + xrp[1];
    f32x2 t2 = unpk2(u.z) + xrp[2];
    f32x2 t3 = unpk2(u.w) + xrp[3];
    f32x2 ep = t0 * a06[0];
    ep = __builtin_elementwise_fma(t1, a06[1], ep);
    ep = __builtin_elementwise_fma(t2, a06[2], ep);
    ep = __builtin_elementwise_fma(t3, a06[3], ep);
    float e0 = fmaf(a04[1], fabsf(t0.y), a04[0] * fabsf(t0.x));
    e0 = fmaf(a04[2], fabsf(t1.x), e0);
    e0 = fmaf(a04[3], fabsf(t1.y), e0);
    float e1 = fmaf(a04[5], fabsf(t2.y), a04[4] * fabsf(t2.x));
    e1 = fmaf(a04[6], fabsf(t3.x), e1);
    e1 = fmaf(a04[7], fabsf(t3.y), e1);
    float e = (ep.x + ep.y) + (e0 + e1);
    e += __shfl_xor(e, 1);
    e += __shfl_xor(e, 2);          // per-head logit (4-lane quad)
    float w = valid ? __builtin_amdgcn_exp2f(e) : 0.f;
    st.s += w;
    f32x2 wv = {w, w};
    st.acc[0] = __builtin_elementwise_fma(wv, t0, st.acc[0]);
    st.acc[1] = __builtin_elementwise_fma(wv, t1, st.acc[1]);
    st.acc[2] = __builtin_elementwise_fma(wv, t2, st.acc[2]);
    st.acc[3] = __builtin_elementwise_fma(wv, t3, st.acc[3]);
}

__global__ __launch_bounds__(256) void node_l1(const int* __restrict__ startA,
                                               const int* __restrict__ degA,
                                               const int* __restrict__ csr_src,
                                               const bf16* __restrict__ xl,
                                               const bf16* __restrict__ xr,
                                               const float* __restrict__ a1,
                                               const float* __restrict__ b1,
                                               bf16* __restrict__ hb) {
    int wid = (blockIdx.x * 256 + threadIdx.x) >> 6;
    int lane = threadIdx.x & 63;
    int g = lane >> 4, t = lane & 15;
    unsigned cB = (unsigned)t * 16;
    int j0 = startA[wid];
    int deg = degA[wid];
    unsigned rowB = (unsigned)csr_src[j0 + min(lane, deg - 1)] << 8;
    const char* xlb = (const char*)xl;
    f32x2 xrp[4];
    {
        uint4 raw = *(const uint4*)((const char*)xr + ((unsigned)wid << 8) + cB);
        xrp[0] = unpk2(raw.x); xrp[1] = unpk2(raw.y);
        xrp[2] = unpk2(raw.z); xrp[3] = unpk2(raw.w);
    }
    f32x2 a06[4];
    float a04[8];
    {
        f32x4 lo = *reinterpret_cast<const f32x4*>(a1 + t * 8);
        f32x4 hi = *reinterpret_cast<const f32x4*>(a1 + t * 8 + 4);
        float af[8];
#pragma unroll
        for (int k = 0; k < 4; k++) { af[k] = lo[k]; af[k + 4] = hi[k]; }
#pragma unroll
        for (int j = 0; j < 4; j++) {
            a06[j].x = af[2 * j] * C06;
            a06[j].y = af[2 * j + 1] * C06;
        }
#pragma unroll
        for (int k = 0; k < 8; k++) a04[k] = af[k] * C04;
    }
    L1S st; st.s = 0.f;
    f32x2 z2 = {0.f, 0.f};
#pragma unroll
    for (int k = 0; k < 4; k++) st.acc[k] = z2;
    int nb = (deg + 3) >> 2;      // 4 edges per batch, one per 16-lane group
    uint4 u[8];
#pragma unroll
    for (int i = 0; i < 4; i++) {
        int pp = min(i * 4 + g, deg - 1);     // <= 31, shfl-safe
        u[i] = *(const uint4*)(xlb + (__shfl(rowB, pp) + cB));
    }
    if (nb > 4) {
#pragma unroll
        for (int i = 4; i < 8; i++) {
            int pp = min(i * 4 + g, deg - 1); // <= 31, shfl-safe
            u[i] = *(const uint4*)(xlb + (__shfl(rowB, pp) + cB));
        }
    }
    l1_consume(u[0], g < deg, xrp, a06, a04, st);
    if (nb > 1) l1_consume(u[1], 4 + g < deg, xrp, a06, a04, st);
    if (nb > 2) l1_consume(u[2], 8 + g < deg, xrp, a06, a04, st);
    if (nb > 3) l1_consume(u[3], 12 + g < deg, xrp, a06, a04, st);
    if (nb > 4) {
        l1_consume(u[4], 16 + g < deg, xrp, a06, a04, st);
        if (nb > 5) l1_consume(u[5], 20 + g < deg, xrp, a06, a04, st);
        if (nb > 6) l1_consume(u[6], 24 + g < deg, xrp, a06, a04, st);
        if (nb > 7) l1_consume(u[7], 28 + g < deg, xrp, a06, a04, st);
        for (int b = 8; b < nb; b++) {
            int p = b * 4 + g;
            bool valid = p < deg;
            int pp = valid ? p : deg - 1;
            unsigned o = __shfl(rowB, min(pp, 63)) + cB;
            if (pp >= 64) o = (((unsigned)csr_src[j0 + pp]) << 8) + cB;
            uint4 uu = *(const uint4*)(xlb + o);
            l1_consume(uu, valid, xrp, a06, a04, st);
        }
    }
#pragma unroll
    for (int d = 16; d < 64; d <<= 1) {
        st.s += __shfl_xor(st.s, d);
#pragma unroll
        for (int k = 0; k < 4; k++) {
            st.acc[k].x += __shfl_xor(st.acc[k].x, d);
            st.acc[k].y += __shfl_xor(st.acc[k].y, d);
        }
    }
    if (g == 0) {
        float inv = 1.f / st.s;
        unsigned pk[4];
#pragma unroll
        for (int k = 0; k < 4; k++) {
            float o0 = st.acc[k].x * inv - xrp[k].x + b1[t * 8 + 2 * k];
            float o1 = st.acc[k].y * inv - xrp[k].y + b1[t * 8 + 2 * k + 1];
            o0 = o0 > 0.f ? o0 : __expf(o0) - 1.f;
            o1 = o1 > 0.f ? o1 : __expf(o1) - 1.f;
            bf16 r0 = __float2bfloat16(o0), r1 = __float2bfloat16(o1);
            pk[k] = (unsigned)*reinterpret_cast<unsigned short*>(&r0) |
                    ((unsigned)*reinterpret_cast<unsigned short*>(&r1) << 16);
        }
        uint4 w4 = {pk[0], pk[1], pk[2], pk[3]};
        *(uint4*)((char*)hb + ((unsigned)wid << 8) + cB) = w4;
    }
}

// ---- K6: GEMM2 dual (LDS-staged 24KB weights, same swizzle scheme). ----
__global__ __launch_bounds__(256) void gemm2(const bf16* __restrict__ h,
                                             const bf16* __restrict__ wT,
                                             bf16* __restrict__ outL,
                                             bf16* __restrict__ outR) {
    __shared__ __align__(16) char smem[24576];   // 96 rows x 256B
    const uint4* wsrc = (const uint4*)wT;
#pragma unroll
    for (int i = 0; i < 6; i++) {
        int idx = i * 256 + threadIdx.x;
        uint4 v = wsrc[idx];
        int r = idx >> 4;
        int c = (idx & 15) << 4;
        *(uint4*)(smem + r * 256 + (c ^ ((r & 7) << 4))) = v;
    }
    __syncthreads();
    int wave = threadIdx.x >> 6;
    int lane = threadIdx.x & 63;
    int tile = blockIdx.x * 4 + wave;
    if (tile >= MTILES) return;
    int row0 = tile * 16;
    int l16 = lane & 15, quad = lane >> 4;
    f32x4 z = {0.f, 0.f, 0.f, 0.f};
    f32x4 accl[3], accr[3];
#pragma unroll
    for (int i = 0; i < 3; i++) { accl[i] = z; accr[i] = z; }
    const bf16* hrow = h + (size_t)(row0 + l16) * 128 + quad * 8;
#pragma unroll
    for (int k0 = 0; k0 < 128; k0 += 32) {
        bf16x8 a = *reinterpret_cast<const bf16x8*>(hrow + k0);
        int cc = k0 * 2 + quad * 16;
        int sw = cc ^ ((l16 & 7) << 4);
#pragma unroll
        for (int ct = 0; ct < 3; ct++) {
            int rl = ct * 16 + l16;
            bf16x8 bl = *(const bf16x8*)(smem + rl * 256 + sw);
            bf16x8 br = *(const bf16x8*)(smem + 12288 + rl * 256 + sw);
            accl[ct] = __builtin_amdgcn_mfma_f32_16x16x32_bf16(a, bl, accl[ct], 0, 0, 0);
            accr[ct] = __builtin_amdgcn_mfma_f32_16x16x32_bf16(a, br, accr[ct], 0, 0, 0);
        }
    }
#pragma unroll
    for (int ct = 0; ct < 3; ct++)
#pragma unroll
        for (int r = 0; r < 4; r++) {
            size_t o = (size_t)(row0 + quad * 4 + r) * CLSP + ct * 16 + l16;
            outL[o] = __float2bfloat16(accl[ct][r]);
            outR[o] = __float2bfloat16(accr[ct][r]);
        }
}

// ---- K7: layer 2 fused. One wave/node, 8 lanes/edge, up to 32 edges in flight. ----
struct L2S { float s; f32x2 acc[3]; };
__device__ __forceinline__ void l2_consume(U3 u, bool valid, const f32x2* xrp,
                                           const f32x2* a06, const float* a04, L2S& st) {
    f32x2 t0 = unpk2(u.x) + xrp[0];
    f32x2 t1 = unpk2(u.y) + xrp[1];
    f32x2 t2 = unpk2(u.z) + xrp[2];
    f32x2 ep = t0 * a06[0];
    ep = __builtin_elementwise_fma(t1, a06[1], ep);
    ep = __builtin_elementwise_fma(t2, a06[2], ep);
    float es = fmaf(a04[1], fabsf(t0.y), a04[0] * fabsf(t0.x));
    es = fmaf(a04[2], fabsf(t1.x), es);
    es = fmaf(a04[3], fabsf(t1.y), es);
    es = fmaf(a04[4], fabsf(t2.x), es);
    es = fmaf(a04[5], fabsf(t2.y), es);
    float e = (ep.x + ep.y) + es;
    e += __shfl_xor(e, 1);
    e += __shfl_xor(e, 2);
    e += __shfl_xor(e, 4);          // full 48-ch logit (8-lane group)
    float w = valid ? __builtin_amdgcn_exp2f(e) : 0.f;
    st.s += w;
    f32x2 wv = {w, w};
    st.acc[0] = __builtin_elementwise_fma(wv, t0, st.acc[0]);
    st.acc[1] = __builtin_elementwise_fma(wv, t1, st.acc[1]);
    st.acc[2] = __builtin_elementwise_fma(wv, t2, st.acc[2]);
}

__global__ __launch_bounds__(256) void node_l2(const int* __restrict__ startA,
                                               const int* __restrict__ degA,
                                               const int* __restrict__ csr_src,
                                               const bf16* __restrict__ xl2,
                                               const bf16* __restrict__ xr2,
                                               const float* __restrict__ a2,
                                               const float* __restrict__ b2,
                                               float* __restrict__ out) {
    int wid = (blockIdx.x * 256 + threadIdx.x) >> 6;
    int lane = threadIdx.x & 63;
    int g = lane >> 3, t = lane & 7;
    unsigned cB = (unsigned)t * 12;
    int j0 = startA[wid];
    int deg = degA[wid];
    unsigned rowB = (unsigned)csr_src[j0 + min(lane, deg - 1)] * 96u;
    const char* xlb = (const char*)xl2;
    f32x2 xrp[3];
    {
        U3 raw = *(const U3*)((const char*)xr2 + (unsigned)wid * 96u + cB);
        xrp[0] = unpk2(raw.x); xrp[1] = unpk2(raw.y); xrp[2] = unpk2(raw.z);
    }
    int c = t * 6;
    f32x2 a06[3];
    float a04[6];
#pragma unroll
    for (int k = 0; k < 6; k++) {
        float av = (c + k < CLS) ? a2[c + k] : 0.f;
        a04[k] = av * C04;
        if (k & 1) a06[k >> 1].y = av * C06; else a06[k >> 1].x = av * C06;
    }
    L2S st; st.s = 0.f;
    f32x2 z2 = {0.f, 0.f};
#pragma unroll
    for (int k = 0; k < 3; k++) st.acc[k] = z2;
    int nb = (deg + 7) >> 3;      // 8 edges per batch, one per 8-lane group
    U3 u[4];
#pragma unroll
    for (int i = 0; i < 2; i++) {
        int pp = min(i * 8 + g, deg - 1);     // <= 31, shfl-safe
        u[i] = *(const U3*)(xlb + (__shfl(rowB, pp) + cB));
    }
    if (nb > 2) {
#pragma unroll
        for (int i = 2; i < 4; i++) {
            int pp = min(i * 8 + g, deg - 1); // <= 31, shfl-safe
            u[i] = *(const U3*)(xlb + (__shfl(rowB, pp) + cB));
        }
    }
    l2_consume(u[0], g < deg, xrp, a06, a04, st);
    if (nb > 1) l2_consume(u[1], 8 + g < deg, xrp, a06, a04, st);
    if (nb > 2) {
        l2_consume(u[2], 16 + g < deg, xrp, a06, a04, st);
        if (nb > 3) l2_consume(u[3], 24 + g < deg, xrp, a06, a04, st);
        for (int b = 4; b < nb; b++) {
            int p = b * 8 + g;
            bool valid = p < deg;
            int pp = valid ? p : deg - 1;
            unsigned o = __shfl(rowB, min(pp, 63)) + cB;
            if (pp >= 64) o = (unsigned)csr_src[j0 + pp] * 96u + cB;
            U3 uu = *(const U3*)(xlb + o);
            l2_consume(uu, valid, xrp, a06, a04, st);
        }
    }
#pragma unroll
    for (int d = 8; d < 64; d <<= 1) {
        st.s += __shfl_xor(st.s, d);
#pragma unroll
        for (int k = 0; k < 3; k++) {
            st.acc[k].x += __shfl_xor(st.acc[k].x, d);
            st.acc[k].y += __shfl_xor(st.acc[k].y, d);
        }
    }
    float inv = 1.f / st.s;
    float q[6];
    float mx = -3e38f;
#pragma unroll
    for (int k = 0; k < 6; k++) {
        bool val = (c + k < CLS);
        float av = (k & 1) ? st.acc[k >> 1].y : st.acc[k >> 1].x;
        float xv = (k & 1) ? xrp[k >> 1].y : xrp[k >> 1].x;
        q[k] = val ? (av * inv - xv + b2[c + k]) : -3e38f;
        mx = fmaxf(mx, q[k]);
    }
    mx = fmaxf(mx, __shfl_xor(mx, 1));
    mx = fmaxf(mx, __shfl_xor(mx, 2));
    mx = fmaxf(mx, __shfl_xor(mx, 4));
    float se = 0.f;
#pragma unroll
    for (int k = 0; k < 6; k++) if (c + k < CLS) se += __expf(q[k] - mx);
    se += __shfl_xor(se, 1);
    se += __shfl_xor(se, 2);
    se += __shfl_xor(se, 4);
    float ls = mx + __logf(se);
    if (g == 0) {
        float* o = out + (size_t)wid * CLS + c;
#pragma unroll
        for (int k = 0; k < 6; k++)
            if (c + k < CLS) o[k] = q[k] - ls;
    }
}

extern "C" void kernel_launch(void* const* d_in, const int* in_sizes, int n_in,
                              void* d_out, int out_size, void* d_ws, size_t ws_size,
                              hipStream_t stream) {
    const float* x   = (const float*)d_in[0];
    const int*   ei  = (const int*)d_in[1];
    const float* w1l = (const float*)d_in[2];
    const float* w1r = (const float*)d_in[3];
    const float* a1  = (const float*)d_in[4];
    const float* b1  = (const float*)d_in[5];
    const float* w2l = (const float*)d_in[6];
    const float* w2r = (const float*)d_in[7];
    const float* a2  = (const float*)d_in[8];
    const float* b2  = (const float*)d_in[9];
    float* out = (float*)d_out;

    // Workspace layout (total ~67.8 MB):
    char* base = (char*)d_ws;
    int*   bcursor = (int*)(base + 0);             //       784 B (zeroed by prep)
    int*   startA  = (int*)(base + 1024);          //   200,000 B
    int*   degA    = (int*)(base + 201024);        //   200,000 B
    uint2* tmp     = (uint2*)(base + 401024);      // 12,845,056 B (NBUCK*BCAP*8)
    int*   csr_src = (int*)(base + 13246080);      //  6,422,528 B (NBUCK*BCAP*4)
    bf16*  xl1     = (bf16*)(base + 19668608);     // 25,600,000 B (xl1|xr1)
    bf16*  hb      = (bf16*)(base + 45268608);     // 12,800,000 B
    bf16*  xl2p    = (bf16*)(base + 58068608);     //  9,600,000 B (xl2p|xr2p, stride 48)
    bf16*  wT1     = (bf16*)(base + 67668608);     //     65,536 B
    bf16*  wT2     = (bf16*)(base + 67734144);     //     24,576 B
    bf16* xr1  = xl1 + (size_t)NN * 128;
    bf16* xr2p = xl2p + (size_t)NN * CLSP;

    prep<<<PREPB, 256, 0, stream>>>(w1l, w1r, w2l, w2r, wT1, wT2, bcursor);
    gemm1_scatter<<<GB1 + KAB, 256, 0, stream>>>(x, wT1, xl1, xr1, ei, bcursor, tmp);
    bucket_sort<<<NBUCK, 256, 0, stream>>>(bcursor, tmp, csr_src, startA, degA);
    node_l1<<<(NN * 64) / 256, 256, 0, stream>>>(startA, degA, csr_src, xl1, xr1, a1, b1, hb);
    gemm2<<<GB1, 256, 0, stream>>>(hb, wT2, xl2p, xr2p);
    node_l2<<<(NN * 64) / 256, 256, 0, stream>>>(startA, degA, csr_src, xl2p, xr2p, a2, b2, out);
}